// Round 7
// baseline (126.566 us; speedup 1.0000x reference)
//
#include <hip/hip_runtime.h>

typedef unsigned short u16;
typedef unsigned int u32;
typedef unsigned long long u64;
typedef __attribute__((ext_vector_type(8))) short bf16x8;
typedef __attribute__((ext_vector_type(4))) float f32x4;

#define CCH 2048

__device__ __forceinline__ u16 f2bf(float f) {
    unsigned int x = __float_as_uint(f);
    unsigned int r = (x + 0x7fffu + ((x >> 16) & 1u)) >> 16;
    return (u16)r;
}

__device__ __forceinline__ void gload_lds16(const u16* g, u16* l) {
    __builtin_amdgcn_global_load_lds((const __attribute__((address_space(1))) void*)g,
                                     (__attribute__((address_space(3))) void*)l, 16, 0, 0);
}

// ---------- PREP: convert W1,W2,Wo -> bf16 | WvSum | x transpose ----------
__global__ void k_prep(const float* __restrict__ W1, const float* __restrict__ W2,
                       const float* __restrict__ Wo, const float* __restrict__ Wv,
                       const float* __restrict__ bv, const float* __restrict__ x,
                       u16* __restrict__ W1b, u16* __restrict__ W2b, u16* __restrict__ Wob,
                       u16* __restrict__ WvSumb, float* __restrict__ bvSum,
                       u16* __restrict__ xTb) {
    int b = blockIdx.x;
    int t = threadIdx.x;
    __shared__ float ftile[32][33];
    if (b < 12288) {
        long base = (long)b * 1024 + t * 4;
        const float* src; u16* dst; long off;
        if (base < 4194304)      { src = W1; dst = W1b; off = base; }
        else if (base < 8388608) { src = W2; dst = W2b; off = base - 4194304; }
        else                     { src = Wo; dst = Wob; off = base - 8388608; }
        float4 v = *(const float4*)&src[off];
        u64 p = (u64)f2bf(v.x) | ((u64)f2bf(v.y) << 16)
              | ((u64)f2bf(v.z) << 32) | ((u64)f2bf(v.w) << 48);
        *(u64*)&dst[off] = p;
    } else if (b < 12800) {
        int tt = (b - 12288) * 256 + t;
        int j = tt >> 11;
        float s = 0.f;
        #pragma unroll 8
        for (int m = 0; m < 32; ++m) s += Wv[(m * 64 + j) * CCH + (tt & 2047)];
        WvSumb[tt] = f2bf(s);
        if (tt < 64) {
            float bb = 0.f;
            for (int m = 0; m < 32; ++m) bb += bv[m * 64 + tt];
            bvSum[tt] = bb;
        }
    } else {
        int bb = b - 12800;
        int cb = bb & 31, q = bb >> 5;
        int c0 = cb * 64;
        u32* xT32 = (u32*)xTb;
        #pragma unroll
        for (int half = 0; half < 2; ++half) {
            int ch = c0 + half * 32;
            #pragma unroll
            for (int k = 0; k < 4; ++k) {
                int i = t + k * 256;
                ftile[i & 31][i >> 5] = x[q * 65536 + (ch + (i >> 5)) * 32 + (i & 31)];
            }
            __syncthreads();
            #pragma unroll
            for (int k = 0; k < 2; ++k) {
                int i = t + k * 256;
                int s = i >> 4, cp = i & 15;
                u32 val = (u32)f2bf(ftile[s][cp * 2]) | ((u32)f2bf(ftile[s][cp * 2 + 1]) << 16);
                xT32[(size_t)(q * 32 + s) * 1024 + (ch >> 1) + cp] = val;
            }
            __syncthreads();
        }
    }
}

// ---------- Sv GEMM: P[kc][j][col] = sum_k WvSumb[j][k] * xTb[col][k] ----------
__global__ __launch_bounds__(256) void k_sv_gemm(const u16* __restrict__ A, const u16* __restrict__ B,
                                                 float* __restrict__ P) {
    int n0 = blockIdx.x * 64;
    int kc = blockIdx.y;
    int t = threadIdx.x;
    int lane = t & 63, wid = t >> 6;
    int wm = wid * 16;
    int l15 = lane & 15, lhi = lane >> 4, sw = l15 & 7;
    int offk[2] = { ((lhi) ^ sw) * 8, ((4 + lhi) ^ sw) * 8 };
    __shared__ u16 At[2][64 * 64];
    __shared__ u16 Bt[2][64 * 64];
    f32x4 z = {0.f, 0.f, 0.f, 0.f};
    f32x4 acc[4] = {z, z, z, z};
    int srow = t >> 3, scol = ((t & 7) ^ (srow & 7)) * 8;
    int kbase = kc * 512;

    auto STAGE = [&](int p, int k0) {
        #pragma unroll
        for (int i = 0; i < 2; ++i) {
            gload_lds16(A + (size_t)(i * 32 + srow) * CCH + k0 + scol, &At[p][i * 2048 + t * 8]);
            gload_lds16(B + (size_t)(n0 + i * 32 + srow) * CCH + k0 + scol, &Bt[p][i * 2048 + t * 8]);
        }
    };
    STAGE(0, kbase);
    __syncthreads();
    int cur = 0;
    for (int kt = 0; kt < 8; ++kt) {
        if (kt < 7) STAGE(cur ^ 1, kbase + (kt + 1) * 64);
        #pragma unroll
        for (int ks = 0; ks < 2; ++ks) {
            bf16x8 af = *(const bf16x8*)&At[cur][(wm + l15) * 64 + offk[ks]];
            #pragma unroll
            for (int fn = 0; fn < 4; ++fn) {
                bf16x8 bf = *(const bf16x8*)&Bt[cur][(fn * 16 + l15) * 64 + offk[ks]];
                acc[fn] = __builtin_amdgcn_mfma_f32_16x16x32_bf16(af, bf, acc[fn], 0, 0, 0);
            }
        }
        __syncthreads();
        cur ^= 1;
    }
    #pragma unroll
    for (int fn = 0; fn < 4; ++fn)
        #pragma unroll
        for (int r = 0; r < 4; ++r) {
            int j = wm + lhi * 4 + r;
            int col = n0 + fn * 16 + l15;
            P[kc * 65536 + j * 1024 + col] = acc[fn][r];
        }
}

// ---------- Sv reduce ----------
__global__ void k_sv_reduce(const float* __restrict__ P, const float* __restrict__ bvSum,
                            u16* __restrict__ Svb) {
    int idx0 = blockIdx.x * 1024 + threadIdx.x;
    #pragma unroll
    for (int k = 0; k < 4; ++k) {
        int idx = idx0 + k * 256;
        int j = idx >> 10, col = idx & 1023;
        float v = bvSum[j];
        #pragma unroll
        for (int kc = 0; kc < 4; ++kc) v += P[kc * 65536 + idx];
        Svb[(size_t)(col >> 5) * CCH + j * 32 + (col & 31)] = f2bf(v);
    }
}

// ---------- T GEMM: P[kc][o][q] = sum_k Wob[o][k] * Svb[q][k] ----------
__global__ __launch_bounds__(256) void k_t_gemm(const u16* __restrict__ A, const u16* __restrict__ B,
                                                float* __restrict__ P) {
    int m0 = blockIdx.x * 128;
    int kc = blockIdx.y;
    int t = threadIdx.x;
    int lane = t & 63, wid = t >> 6;
    int wm = wid * 32;
    int l15 = lane & 15, lhi = lane >> 4, sw = l15 & 7;
    int offk[2] = { ((lhi) ^ sw) * 8, ((4 + lhi) ^ sw) * 8 };
    __shared__ u16 At[2][128 * 64];
    __shared__ u16 Bt[2][32 * 64];
    f32x4 z = {0.f, 0.f, 0.f, 0.f};
    f32x4 acc[2][2] = {{z, z}, {z, z}};
    int srow = t >> 3, scol = ((t & 7) ^ (srow & 7)) * 8;
    int kbase = kc * 512;

    auto STAGE = [&](int p, int k0) {
        #pragma unroll
        for (int i = 0; i < 4; ++i)
            gload_lds16(A + (size_t)(m0 + i * 32 + srow) * CCH + k0 + scol, &At[p][i * 2048 + t * 8]);
        gload_lds16(B + (size_t)srow * CCH + k0 + scol, &Bt[p][t * 8]);
    };
    STAGE(0, kbase);
    __syncthreads();
    int cur = 0;
    for (int kt = 0; kt < 8; ++kt) {
        if (kt < 7) STAGE(cur ^ 1, kbase + (kt + 1) * 64);
        #pragma unroll
        for (int ks = 0; ks < 2; ++ks) {
            bf16x8 af[2], bf[2];
            #pragma unroll
            for (int fm = 0; fm < 2; ++fm)
                af[fm] = *(const bf16x8*)&At[cur][(wm + fm * 16 + l15) * 64 + offk[ks]];
            #pragma unroll
            for (int fn = 0; fn < 2; ++fn)
                bf[fn] = *(const bf16x8*)&Bt[cur][(fn * 16 + l15) * 64 + offk[ks]];
            #pragma unroll
            for (int fm = 0; fm < 2; ++fm)
                #pragma unroll
                for (int fn = 0; fn < 2; ++fn)
                    acc[fm][fn] = __builtin_amdgcn_mfma_f32_16x16x32_bf16(af[fm], bf[fn], acc[fm][fn], 0, 0, 0);
        }
        __syncthreads();
        cur ^= 1;
    }
    #pragma unroll
    for (int fm = 0; fm < 2; ++fm)
        #pragma unroll
        for (int fn = 0; fn < 2; ++fn)
            #pragma unroll
            for (int r = 0; r < 4; ++r) {
                int mg = m0 + wm + fm * 16 + lhi * 4 + r;
                int cg = fn * 16 + l15;
                P[kc * 65536 + mg * 32 + cg] = acc[fm][fn][r];
            }
}

// ---------- fused T reduce + LN1 stats ----------
__global__ void k_t_reduce_ln1(const float* __restrict__ P, const float* __restrict__ bo,
                               const float* __restrict__ x, float* __restrict__ Tm,
                               float* __restrict__ p1, float* __restrict__ p2) {
    int q = blockIdx.x, ch = blockIdx.y;
    int t = threadIdx.x;
    int c = ch * 256 + t;
    float T = bo[c];
    #pragma unroll
    for (int kc = 0; kc < 4; ++kc) T += P[kc * 65536 + c * 32 + q];
    Tm[q * CCH + c] = T;
    float T16 = 16.f * T;
    const float* xr = x + (size_t)q * 65536 + (size_t)c * 32;
    float sum = 0.f, ssq = 0.f;
    #pragma unroll
    for (int s4 = 0; s4 < 8; ++s4) {
        float4 xv = *(const float4*)&xr[s4 * 4];
        float v0 = T16 + xv.x, v1 = T16 + xv.y, v2 = T16 + xv.z, v3 = T16 + xv.w;
        sum += v0 + v1 + v2 + v3;
        ssq += v0 * v0 + v1 * v1 + v2 * v2 + v3 * v3;
    }
    #pragma unroll
    for (int off = 32; off > 0; off >>= 1) {
        sum += __shfl_down(sum, off);
        ssq += __shfl_down(ssq, off);
    }
    __shared__ float rs[4], rq[4];
    if ((t & 63) == 0) { rs[t >> 6] = sum; rq[t >> 6] = ssq; }
    __syncthreads();
    if (t == 0) {
        p1[q * 8 + ch] = rs[0] + rs[1] + rs[2] + rs[3];
        p2[q * 8 + ch] = rq[0] + rq[1] + rq[2] + rq[3];
    }
}

// ---------- LN1 apply (finish inline) ----------
__global__ void k_ln1apply(const float* __restrict__ Tm, const float* __restrict__ x,
                           const float* __restrict__ p1, const float* __restrict__ p2,
                           const float* __restrict__ lnw, const float* __restrict__ lnb,
                           float* __restrict__ h1, u16* __restrict__ h1b) {
    int q = blockIdx.x, cb = blockIdx.y;
    int t = threadIdx.x;
    float S = 0.f, Q = 0.f;
    #pragma unroll
    for (int cch = 0; cch < 8; ++cch) { S += p1[q * 8 + cch]; Q += p2[q * 8 + cch]; }
    float mu = S * (1.f / 65536.f);
    float rstd = rsqrtf(Q * (1.f / 65536.f) - mu * mu + 1e-5f);
    __shared__ u16 tile[32 * 132];
    for (int j = 0; j < 16; ++j) {
        int i = cb * 4096 + j * 256 + t;
        float v = 16.f * Tm[q * CCH + (i >> 5)] + x[q * 65536 + i];
        float g = (v - mu) * rstd * lnw[i] + lnb[i];
        h1[q * 65536 + i] = g;
        int cl = (j * 256 + t) >> 5;
        tile[(i & 31) * 132 + cl] = f2bf(g);
    }
    __syncthreads();
    for (int j = 0; j < 16; ++j) {
        int idx = j * 256 + t;
        int s = idx >> 7, cl = idx & 127;
        h1b[(size_t)(q * 32 + s) * CCH + cb * 128 + cl] = tile[s * 132 + cl];
    }
}

// ---------- MFMA GEMM split-K 4, 128x64 tile: P[kc][m][col] ----------
__global__ __launch_bounds__(256) void k_mfma_gemm_sk(
        const u16* __restrict__ A, const u16* __restrict__ B,
        float* __restrict__ P, int ldc) {
    int m0 = blockIdx.x * 128;
    int n0 = blockIdx.y * 64;
    int kc = blockIdx.z;
    int t = threadIdx.x;
    int lane = t & 63, wid = t >> 6;
    int wm = (wid >> 1) * 64, wn = (wid & 1) * 32;
    int l15 = lane & 15, lhi = lane >> 4, sw = l15 & 7;
    int offk[2] = { ((lhi) ^ sw) * 8, ((4 + lhi) ^ sw) * 8 };

    __shared__ u16 Atile[2][128 * 64];
    __shared__ u16 Btile[2][64 * 64];

    f32x4 z = {0.f, 0.f, 0.f, 0.f};
    f32x4 acc[4][2] = {{z, z}, {z, z}, {z, z}, {z, z}};

    int srow = t >> 3;
    int scol = ((t & 7) ^ (srow & 7)) * 8;   // pre-swizzled source chunk (rule #21)
    int kbase = kc * 512;

    auto STAGE = [&](int p, int k0) {
        #pragma unroll
        for (int i = 0; i < 4; ++i)
            gload_lds16(A + (size_t)(m0 + i * 32 + srow) * CCH + k0 + scol,
                        &Atile[p][i * 2048 + t * 8]);
        #pragma unroll
        for (int i = 0; i < 2; ++i)
            gload_lds16(B + (size_t)(n0 + i * 32 + srow) * CCH + k0 + scol,
                        &Btile[p][i * 2048 + t * 8]);
    };

    STAGE(0, kbase);
    __syncthreads();
    int cur = 0;
    for (int kt = 0; kt < 8; ++kt) {
        if (kt < 7) STAGE(cur ^ 1, kbase + (kt + 1) * 64);
        #pragma unroll
        for (int ks = 0; ks < 2; ++ks) {
            bf16x8 af[4], bf[2];
            #pragma unroll
            for (int fm = 0; fm < 4; ++fm)
                af[fm] = *(const bf16x8*)&Atile[cur][(wm + fm * 16 + l15) * 64 + offk[ks]];
            #pragma unroll
            for (int fn = 0; fn < 2; ++fn)
                bf[fn] = *(const bf16x8*)&Btile[cur][(wn + fn * 16 + l15) * 64 + offk[ks]];
            #pragma unroll
            for (int fm = 0; fm < 4; ++fm)
                #pragma unroll
                for (int fn = 0; fn < 2; ++fn)
                    acc[fm][fn] = __builtin_amdgcn_mfma_f32_16x16x32_bf16(
                        af[fm], bf[fn], acc[fm][fn], 0, 0, 0);
        }
        __syncthreads();
        cur ^= 1;
    }

    #pragma unroll
    for (int fm = 0; fm < 4; ++fm)
        #pragma unroll
        for (int fn = 0; fn < 2; ++fn)
            #pragma unroll
            for (int r = 0; r < 4; ++r) {
                int mg = m0 + wm + fm * 16 + lhi * 4 + r;
                int cg = n0 + wn + fn * 16 + l15;
                P[(size_t)kc * 2097152 + (size_t)mg * ldc + cg] = acc[fm][fn][r];
            }
}

// ---------- G1 reduce: Y1b[tok][o] = bf16(relu(P0+P1+P2+P3)) ----------
__global__ void k_g1_reduce(const float* __restrict__ P, u16* __restrict__ Y1b) {
    int idx = (blockIdx.x * 256 + threadIdx.x) * 4;
    float4 a = *(const float4*)&P[idx];
    float4 b = *(const float4*)&P[2097152 + idx];
    float4 c = *(const float4*)&P[4194304 + idx];
    float4 d = *(const float4*)&P[6291456 + idx];
    u64 p = (u64)f2bf(fmaxf(a.x + b.x + c.x + d.x, 0.f))
          | ((u64)f2bf(fmaxf(a.y + b.y + c.y + d.y, 0.f)) << 16)
          | ((u64)f2bf(fmaxf(a.z + b.z + c.z + d.z, 0.f)) << 32)
          | ((u64)f2bf(fmaxf(a.w + b.w + c.w + d.w, 0.f)) << 48);
    *(u64*)&Y1b[idx] = p;
}

// ---------- fused G2 reduce + residual + LN2 stats ----------
__global__ void k_g2_ln2(const float* __restrict__ P, const float* __restrict__ h1,
                         float* __restrict__ out, float* __restrict__ p1, float* __restrict__ p2) {
    int q = blockIdx.x, ch = blockIdx.y;
    int t = threadIdx.x;
    int o = ch * 256 + t;
    size_t pbase = (size_t)o * 1024 + q * 32;
    const float* hr = h1 + (size_t)q * 65536 + (size_t)o * 32;
    float* orow = out + (size_t)q * 65536 + (size_t)o * 32;
    float sum = 0.f, ssq = 0.f;
    #pragma unroll
    for (int s4 = 0; s4 < 8; ++s4) {
        float4 a = *(const float4*)&P[pbase + s4 * 4];
        float4 b = *(const float4*)&P[2097152 + pbase + s4 * 4];
        float4 c = *(const float4*)&P[4194304 + pbase + s4 * 4];
        float4 d = *(const float4*)&P[6291456 + pbase + s4 * 4];
        float4 h = *(const float4*)&hr[s4 * 4];
        float4 v;
        v.x = a.x + b.x + c.x + d.x + h.x;
        v.y = a.y + b.y + c.y + d.y + h.y;
        v.z = a.z + b.z + c.z + d.z + h.z;
        v.w = a.w + b.w + c.w + d.w + h.w;
        *(float4*)&orow[s4 * 4] = v;
        sum += v.x + v.y + v.z + v.w;
        ssq += v.x * v.x + v.y * v.y + v.z * v.z + v.w * v.w;
    }
    #pragma unroll
    for (int off = 32; off > 0; off >>= 1) {
        sum += __shfl_down(sum, off);
        ssq += __shfl_down(ssq, off);
    }
    __shared__ float rs[4], rq[4];
    if ((t & 63) == 0) { rs[t >> 6] = sum; rq[t >> 6] = ssq; }
    __syncthreads();
    if (t == 0) {
        p1[q * 8 + ch] = rs[0] + rs[1] + rs[2] + rs[3];
        p2[q * 8 + ch] = rq[0] + rq[1] + rq[2] + rq[3];
    }
}

// ---------- LN2 apply (finish inline), in-place ----------
__global__ void k_ln2apply(float* __restrict__ io, const float* __restrict__ p1,
                           const float* __restrict__ p2,
                           const float* __restrict__ lnw, const float* __restrict__ lnb) {
    int q = blockIdx.x, cb = blockIdx.y;
    int t = threadIdx.x;
    float S = 0.f, Q = 0.f;
    #pragma unroll
    for (int cch = 0; cch < 8; ++cch) { S += p1[q * 8 + cch]; Q += p2[q * 8 + cch]; }
    float mu = S * (1.f / 65536.f);
    float rstd = rsqrtf(Q * (1.f / 65536.f) - mu * mu + 1e-5f);
    for (int j = 0; j < 16; ++j) {
        int i = cb * 4096 + j * 256 + t;
        float v = io[q * 65536 + i];
        io[q * 65536 + i] = (v - mu) * rstd * lnw[i] + lnb[i];
    }
}

extern "C" void kernel_launch(void* const* d_in, const int* in_sizes, int n_in,
                              void* d_out, int out_size, void* d_ws, size_t ws_size,
                              hipStream_t stream) {
    const float* x    = (const float*)d_in[0];
    const float* Wv   = (const float*)d_in[6];
    const float* bv   = (const float*)d_in[7];
    const float* Wo   = (const float*)d_in[8];
    const float* bo   = (const float*)d_in[9];
    const float* W1   = (const float*)d_in[10];
    const float* W2   = (const float*)d_in[11];
    const float* ln1w = (const float*)d_in[12];
    const float* ln1b = (const float*)d_in[13];
    const float* ln2w = (const float*)d_in[14];
    const float* ln2b = (const float*)d_in[15];
    float* out = (float*)d_out;

    float* ws    = (float*)d_ws;
    float* bvSum = ws;                    // 64
    float* p1    = ws + 128;              // 256
    float* p2    = ws + 384;              // 256
    float* Psv   = ws + 640;              // 262144
    float* Pt    = ws + 262784;           // 262144
    float* Tm    = ws + 524928;           // 65536
    float* h1    = ws + 590464;           // 2097152
    float* Pg    = ws + 2687616;          // 8388608 (4 split-K planes)
    u16* ub      = (u16*)(ws + 11076224);
    u16* WvSumb  = ub;                    // 131072
    u16* xTb     = ub + 131072;           // 2097152
    u16* Svb     = ub + 2228224;          // 65536
    u16* h1b     = ub + 2293760;          // 2097152
    u16* Y1b     = ub + 4390912;          // 2097152
    u16* W1b     = ub + 6488064;          // 4194304
    u16* W2b     = ub + 10682368;         // 4194304
    u16* Wob     = ub + 14876672;         // 4194304  -> ~82.5 MB total

    k_prep<<<13824, 256, 0, stream>>>(W1, W2, Wo, Wv, bv, x, W1b, W2b, Wob, WvSumb, bvSum, xTb);
    k_sv_gemm<<<dim3(16, 4), 256, 0, stream>>>(WvSumb, xTb, Psv);
    k_sv_reduce<<<64, 256, 0, stream>>>(Psv, bvSum, Svb);
    k_t_gemm<<<dim3(16, 4), 256, 0, stream>>>(Wob, Svb, Pt);
    k_t_reduce_ln1<<<dim3(32, 8), 256, 0, stream>>>(Pt, bo, x, Tm, p1, p2);
    k_ln1apply<<<dim3(32, 16), 256, 0, stream>>>(Tm, x, p1, p2, ln1w, ln1b, h1, h1b);
    // GEMM1: M=1024 (tokens) x N=2048 (o), 128x64 tile, split-K 4
    k_mfma_gemm_sk<<<dim3(8, 32, 4), 256, 0, stream>>>(h1b, W1b, Pg, 2048);
    k_g1_reduce<<<2048, 256, 0, stream>>>(Pg, Y1b);
    // GEMM2: M=2048 (o) x N=1024 (tokens), 128x64 tile, split-K 4
    k_mfma_gemm_sk<<<dim3(16, 16, 4), 256, 0, stream>>>(W2b, Y1b, Pg, 1024);
    k_g2_ln2<<<dim3(32, 8), 256, 0, stream>>>(Pg, h1, out, p1, p2);
    k_ln2apply<<<dim3(32, 16), 256, 0, stream>>>(out, p1, p2, ln2w, ln2b);
}

// Round 8
// 110.689 us; speedup vs baseline: 1.1434x; 1.1434x over previous
//
#include <hip/hip_runtime.h>

typedef unsigned short u16;
typedef unsigned int u32;
typedef unsigned long long u64;
typedef __attribute__((ext_vector_type(8))) short bf16x8;
typedef __attribute__((ext_vector_type(4))) float f32x4;

#define CCH 2048

__device__ __forceinline__ u16 f2bf(float f) {
    unsigned int x = __float_as_uint(f);
    unsigned int r = (x + 0x7fffu + ((x >> 16) & 1u)) >> 16;
    return (u16)r;
}

__device__ __forceinline__ void gload_lds16(const u16* g, u16* l) {
    __builtin_amdgcn_global_load_lds((const __attribute__((address_space(1))) void*)g,
                                     (__attribute__((address_space(3))) void*)l, 16, 0, 0);
}

// ---------- PREP: convert W1,W2,Wo -> bf16 | WvSum | x transpose ----------
__global__ void k_prep(const float* __restrict__ W1, const float* __restrict__ W2,
                       const float* __restrict__ Wo, const float* __restrict__ Wv,
                       const float* __restrict__ bv, const float* __restrict__ x,
                       u16* __restrict__ W1b, u16* __restrict__ W2b, u16* __restrict__ Wob,
                       u16* __restrict__ WvSumb, float* __restrict__ bvSum,
                       u16* __restrict__ xTb) {
    int b = blockIdx.x;
    int t = threadIdx.x;
    __shared__ float ftile[32][33];
    if (b < 12288) {
        long base = (long)b * 1024 + t * 4;
        const float* src; u16* dst; long off;
        if (base < 4194304)      { src = W1; dst = W1b; off = base; }
        else if (base < 8388608) { src = W2; dst = W2b; off = base - 4194304; }
        else                     { src = Wo; dst = Wob; off = base - 8388608; }
        float4 v = *(const float4*)&src[off];
        u64 p = (u64)f2bf(v.x) | ((u64)f2bf(v.y) << 16)
              | ((u64)f2bf(v.z) << 32) | ((u64)f2bf(v.w) << 48);
        *(u64*)&dst[off] = p;
    } else if (b < 12800) {
        int tt = (b - 12288) * 256 + t;
        int j = tt >> 11;
        float s = 0.f;
        #pragma unroll 8
        for (int m = 0; m < 32; ++m) s += Wv[(m * 64 + j) * CCH + (tt & 2047)];
        WvSumb[tt] = f2bf(s);
        if (tt < 64) {
            float bb = 0.f;
            for (int m = 0; m < 32; ++m) bb += bv[m * 64 + tt];
            bvSum[tt] = bb;
        }
    } else {
        int bb = b - 12800;
        int cb = bb & 31, q = bb >> 5;
        int c0 = cb * 64;
        u32* xT32 = (u32*)xTb;
        #pragma unroll
        for (int half = 0; half < 2; ++half) {
            int ch = c0 + half * 32;
            #pragma unroll
            for (int k = 0; k < 4; ++k) {
                int i = t + k * 256;
                ftile[i & 31][i >> 5] = x[q * 65536 + (ch + (i >> 5)) * 32 + (i & 31)];
            }
            __syncthreads();
            #pragma unroll
            for (int k = 0; k < 2; ++k) {
                int i = t + k * 256;
                int s = i >> 4, cp = i & 15;
                u32 val = (u32)f2bf(ftile[s][cp * 2]) | ((u32)f2bf(ftile[s][cp * 2 + 1]) << 16);
                xT32[(size_t)(q * 32 + s) * 1024 + (ch >> 1) + cp] = val;
            }
            __syncthreads();
        }
    }
}

// ---------- Sv GEMM: P[kc][j][tok] = sum_{c in chunk} WvSumb[j][c] * xTb[tok][c] ----------
__global__ __launch_bounds__(256) void k_sv_gemm(const u16* __restrict__ A, const u16* __restrict__ B,
                                                 float* __restrict__ P) {
    int n0 = blockIdx.x * 64;
    int kc = blockIdx.y;
    int t = threadIdx.x;
    int lane = t & 63, wid = t >> 6;
    int wm = wid * 16;
    int l15 = lane & 15, lhi = lane >> 4, sw = l15 & 7;
    int offk[2] = { ((lhi) ^ sw) * 8, ((4 + lhi) ^ sw) * 8 };
    __shared__ u16 At[2][64 * 64];
    __shared__ u16 Bt[2][64 * 64];
    f32x4 z = {0.f, 0.f, 0.f, 0.f};
    f32x4 acc[4] = {z, z, z, z};
    int srow = t >> 3, scol = ((t & 7) ^ (srow & 7)) * 8;
    int kbase = kc * 512;

    auto STAGE = [&](int p, int k0) {
        #pragma unroll
        for (int i = 0; i < 2; ++i) {
            gload_lds16(A + (size_t)(i * 32 + srow) * CCH + k0 + scol, &At[p][i * 2048 + t * 8]);
            gload_lds16(B + (size_t)(n0 + i * 32 + srow) * CCH + k0 + scol, &Bt[p][i * 2048 + t * 8]);
        }
    };
    STAGE(0, kbase);
    __syncthreads();
    int cur = 0;
    for (int kt = 0; kt < 8; ++kt) {
        if (kt < 7) STAGE(cur ^ 1, kbase + (kt + 1) * 64);
        #pragma unroll
        for (int ks = 0; ks < 2; ++ks) {
            bf16x8 af = *(const bf16x8*)&At[cur][(wm + l15) * 64 + offk[ks]];
            #pragma unroll
            for (int fn = 0; fn < 4; ++fn) {
                bf16x8 bf = *(const bf16x8*)&Bt[cur][(fn * 16 + l15) * 64 + offk[ks]];
                acc[fn] = __builtin_amdgcn_mfma_f32_16x16x32_bf16(af, bf, acc[fn], 0, 0, 0);
            }
        }
        __syncthreads();
        cur ^= 1;
    }
    #pragma unroll
    for (int fn = 0; fn < 4; ++fn)
        #pragma unroll
        for (int r = 0; r < 4; ++r) {
            int j = wm + lhi * 4 + r;
            int col = n0 + fn * 16 + l15;
            P[kc * 65536 + j * 1024 + col] = acc[fn][r];
        }
}

// ---------- T GEMM: P[kc][o][q] = sum_k Wob[o][k] * Sv[q][k] ----------
// B operand built on the fly from the 4 Psv planes + bvSum (sv_reduce fused in)
__global__ __launch_bounds__(256) void k_t_gemm(const u16* __restrict__ A,
                                                const float* __restrict__ Psv,
                                                const float* __restrict__ bvSum,
                                                float* __restrict__ P) {
    int m0 = blockIdx.x * 128;
    int kc = blockIdx.y;
    int t = threadIdx.x;
    int lane = t & 63, wid = t >> 6;
    int wm = wid * 32;
    int l15 = lane & 15, lhi = lane >> 4, sw = l15 & 7;
    int offk[2] = { ((lhi) ^ sw) * 8, ((4 + lhi) ^ sw) * 8 };
    __shared__ u16 At[2][128 * 64];
    __shared__ u16 Bt[2][32 * 64];
    f32x4 z = {0.f, 0.f, 0.f, 0.f};
    f32x4 acc[2][2] = {{z, z}, {z, z}};
    int srow = t >> 3, scol = ((t & 7) ^ (srow & 7)) * 8;
    int kbase = kc * 512;

    auto STAGE = [&](int p, int k0) {
        #pragma unroll
        for (int i = 0; i < 4; ++i)
            gload_lds16(A + (size_t)(m0 + i * 32 + srow) * CCH + k0 + scol, &At[p][i * 2048 + t * 8]);
        // B: Sv[srow][k..k+7] = bvSum[j] + sum of 4 Psv planes (contiguous fp32)
        int k = k0 + scol;                       // 8-aligned, never crosses j boundary
        int j = k >> 5;
        size_t pb = (size_t)j * 1024 + srow * 32 + (k & 31);
        float4 a0 = *(const float4*)&Psv[pb];
        float4 a1 = *(const float4*)&Psv[65536 + pb];
        float4 a2 = *(const float4*)&Psv[131072 + pb];
        float4 a3 = *(const float4*)&Psv[196608 + pb];
        float4 b0 = *(const float4*)&Psv[pb + 4];
        float4 b1 = *(const float4*)&Psv[65536 + pb + 4];
        float4 b2 = *(const float4*)&Psv[131072 + pb + 4];
        float4 b3 = *(const float4*)&Psv[196608 + pb + 4];
        float bias = bvSum[j];
        float v0 = bias + a0.x + a1.x + a2.x + a3.x;
        float v1 = bias + a0.y + a1.y + a2.y + a3.y;
        float v2 = bias + a0.z + a1.z + a2.z + a3.z;
        float v3 = bias + a0.w + a1.w + a2.w + a3.w;
        float v4 = bias + b0.x + b1.x + b2.x + b3.x;
        float v5 = bias + b0.y + b1.y + b2.y + b3.y;
        float v6 = bias + b0.z + b1.z + b2.z + b3.z;
        float v7 = bias + b0.w + b1.w + b2.w + b3.w;
        uint4 pk;
        pk.x = (u32)f2bf(v0) | ((u32)f2bf(v1) << 16);
        pk.y = (u32)f2bf(v2) | ((u32)f2bf(v3) << 16);
        pk.z = (u32)f2bf(v4) | ((u32)f2bf(v5) << 16);
        pk.w = (u32)f2bf(v6) | ((u32)f2bf(v7) << 16);
        *((uint4*)&Bt[p][t * 8]) = pk;
    };
    STAGE(0, kbase);
    __syncthreads();
    int cur = 0;
    for (int kt = 0; kt < 8; ++kt) {
        if (kt < 7) STAGE(cur ^ 1, kbase + (kt + 1) * 64);
        #pragma unroll
        for (int ks = 0; ks < 2; ++ks) {
            bf16x8 af[2], bf[2];
            #pragma unroll
            for (int fm = 0; fm < 2; ++fm)
                af[fm] = *(const bf16x8*)&At[cur][(wm + fm * 16 + l15) * 64 + offk[ks]];
            #pragma unroll
            for (int fn = 0; fn < 2; ++fn)
                bf[fn] = *(const bf16x8*)&Bt[cur][(fn * 16 + l15) * 64 + offk[ks]];
            #pragma unroll
            for (int fm = 0; fm < 2; ++fm)
                #pragma unroll
                for (int fn = 0; fn < 2; ++fn)
                    acc[fm][fn] = __builtin_amdgcn_mfma_f32_16x16x32_bf16(af[fm], bf[fn], acc[fm][fn], 0, 0, 0);
        }
        __syncthreads();
        cur ^= 1;
    }
    #pragma unroll
    for (int fm = 0; fm < 2; ++fm)
        #pragma unroll
        for (int fn = 0; fn < 2; ++fn)
            #pragma unroll
            for (int r = 0; r < 4; ++r) {
                int mg = m0 + wm + fm * 16 + lhi * 4 + r;
                int cg = fn * 16 + l15;
                P[kc * 65536 + mg * 32 + cg] = acc[fm][fn][r];
            }
}

// ---------- fused T reduce + LN1 stats ----------
__global__ void k_t_reduce_ln1(const float* __restrict__ P, const float* __restrict__ bo,
                               const float* __restrict__ x, float* __restrict__ Tm,
                               float* __restrict__ p1, float* __restrict__ p2) {
    int q = blockIdx.x, ch = blockIdx.y;
    int t = threadIdx.x;
    int c = ch * 256 + t;
    float T = bo[c];
    #pragma unroll
    for (int kc = 0; kc < 4; ++kc) T += P[kc * 65536 + c * 32 + q];
    Tm[q * CCH + c] = T;
    float T16 = 16.f * T;
    const float* xr = x + (size_t)q * 65536 + (size_t)c * 32;
    float sum = 0.f, ssq = 0.f;
    #pragma unroll
    for (int s4 = 0; s4 < 8; ++s4) {
        float4 xv = *(const float4*)&xr[s4 * 4];
        float v0 = T16 + xv.x, v1 = T16 + xv.y, v2 = T16 + xv.z, v3 = T16 + xv.w;
        sum += v0 + v1 + v2 + v3;
        ssq += v0 * v0 + v1 * v1 + v2 * v2 + v3 * v3;
    }
    #pragma unroll
    for (int off = 32; off > 0; off >>= 1) {
        sum += __shfl_down(sum, off);
        ssq += __shfl_down(ssq, off);
    }
    __shared__ float rs[4], rq[4];
    if ((t & 63) == 0) { rs[t >> 6] = sum; rq[t >> 6] = ssq; }
    __syncthreads();
    if (t == 0) {
        p1[q * 8 + ch] = rs[0] + rs[1] + rs[2] + rs[3];
        p2[q * 8 + ch] = rq[0] + rq[1] + rq[2] + rq[3];
    }
}

// ---------- LN1 apply (finish inline) ----------
__global__ void k_ln1apply(const float* __restrict__ Tm, const float* __restrict__ x,
                           const float* __restrict__ p1, const float* __restrict__ p2,
                           const float* __restrict__ lnw, const float* __restrict__ lnb,
                           float* __restrict__ h1, u16* __restrict__ h1b) {
    int q = blockIdx.x, cb = blockIdx.y;
    int t = threadIdx.x;
    float S = 0.f, Q = 0.f;
    #pragma unroll
    for (int cch = 0; cch < 8; ++cch) { S += p1[q * 8 + cch]; Q += p2[q * 8 + cch]; }
    float mu = S * (1.f / 65536.f);
    float rstd = rsqrtf(Q * (1.f / 65536.f) - mu * mu + 1e-5f);
    __shared__ u16 tile[32 * 132];
    for (int j = 0; j < 16; ++j) {
        int i = cb * 4096 + j * 256 + t;
        float v = 16.f * Tm[q * CCH + (i >> 5)] + x[q * 65536 + i];
        float g = (v - mu) * rstd * lnw[i] + lnb[i];
        h1[q * 65536 + i] = g;
        int cl = (j * 256 + t) >> 5;
        tile[(i & 31) * 132 + cl] = f2bf(g);
    }
    __syncthreads();
    for (int j = 0; j < 16; ++j) {
        int idx = j * 256 + t;
        int s = idx >> 7, cl = idx & 127;
        h1b[(size_t)(q * 32 + s) * CCH + cb * 128 + cl] = tile[s * 132 + cl];
    }
}

// ---------- MFMA GEMM split-K 2, 128x64 tile: P[kc][m][col] ----------
__global__ __launch_bounds__(256) void k_mfma_gemm_sk(
        const u16* __restrict__ A, const u16* __restrict__ B,
        float* __restrict__ P, int ldc) {
    int m0 = blockIdx.x * 128;
    int n0 = blockIdx.y * 64;
    int kc = blockIdx.z;
    int t = threadIdx.x;
    int lane = t & 63, wid = t >> 6;
    int wm = (wid >> 1) * 64, wn = (wid & 1) * 32;
    int l15 = lane & 15, lhi = lane >> 4, sw = l15 & 7;
    int offk[2] = { ((lhi) ^ sw) * 8, ((4 + lhi) ^ sw) * 8 };

    __shared__ u16 Atile[2][128 * 64];
    __shared__ u16 Btile[2][64 * 64];

    f32x4 z = {0.f, 0.f, 0.f, 0.f};
    f32x4 acc[4][2] = {{z, z}, {z, z}, {z, z}, {z, z}};

    int srow = t >> 3;
    int scol = ((t & 7) ^ (srow & 7)) * 8;   // pre-swizzled source chunk (rule #21)
    int kbase = kc * 1024;

    auto STAGE = [&](int p, int k0) {
        #pragma unroll
        for (int i = 0; i < 4; ++i)
            gload_lds16(A + (size_t)(m0 + i * 32 + srow) * CCH + k0 + scol,
                        &Atile[p][i * 2048 + t * 8]);
        #pragma unroll
        for (int i = 0; i < 2; ++i)
            gload_lds16(B + (size_t)(n0 + i * 32 + srow) * CCH + k0 + scol,
                        &Btile[p][i * 2048 + t * 8]);
    };

    STAGE(0, kbase);
    __syncthreads();
    int cur = 0;
    for (int kt = 0; kt < 16; ++kt) {
        if (kt < 15) STAGE(cur ^ 1, kbase + (kt + 1) * 64);
        #pragma unroll
        for (int ks = 0; ks < 2; ++ks) {
            bf16x8 af[4], bf[2];
            #pragma unroll
            for (int fm = 0; fm < 4; ++fm)
                af[fm] = *(const bf16x8*)&Atile[cur][(wm + fm * 16 + l15) * 64 + offk[ks]];
            #pragma unroll
            for (int fn = 0; fn < 2; ++fn)
                bf[fn] = *(const bf16x8*)&Btile[cur][(wn + fn * 16 + l15) * 64 + offk[ks]];
            #pragma unroll
            for (int fm = 0; fm < 4; ++fm)
                #pragma unroll
                for (int fn = 0; fn < 2; ++fn)
                    acc[fm][fn] = __builtin_amdgcn_mfma_f32_16x16x32_bf16(
                        af[fm], bf[fn], acc[fm][fn], 0, 0, 0);
        }
        __syncthreads();
        cur ^= 1;
    }

    #pragma unroll
    for (int fm = 0; fm < 4; ++fm)
        #pragma unroll
        for (int fn = 0; fn < 2; ++fn)
            #pragma unroll
            for (int r = 0; r < 4; ++r) {
                int mg = m0 + wm + fm * 16 + lhi * 4 + r;
                int cg = n0 + wn + fn * 16 + l15;
                P[(size_t)kc * 2097152 + (size_t)mg * ldc + cg] = acc[fm][fn][r];
            }
}

// ---------- G1 reduce: Y1b[tok][o] = bf16(relu(P0+P1)) ----------
__global__ void k_g1_reduce(const float* __restrict__ P, u16* __restrict__ Y1b) {
    int idx = (blockIdx.x * 256 + threadIdx.x) * 4;
    float4 a = *(const float4*)&P[idx];
    float4 b = *(const float4*)&P[2097152 + idx];
    u64 p = (u64)f2bf(fmaxf(a.x + b.x, 0.f))
          | ((u64)f2bf(fmaxf(a.y + b.y, 0.f)) << 16)
          | ((u64)f2bf(fmaxf(a.z + b.z, 0.f)) << 32)
          | ((u64)f2bf(fmaxf(a.w + b.w, 0.f)) << 48);
    *(u64*)&Y1b[idx] = p;
}

// ---------- fused G2 reduce + residual + LN2 stats ----------
__global__ void k_g2_ln2(const float* __restrict__ P, const float* __restrict__ h1,
                         float* __restrict__ out, float* __restrict__ p1, float* __restrict__ p2) {
    int q = blockIdx.x, ch = blockIdx.y;
    int t = threadIdx.x;
    int o = ch * 256 + t;
    size_t pbase = (size_t)o * 1024 + q * 32;
    const float* hr = h1 + (size_t)q * 65536 + (size_t)o * 32;
    float* orow = out + (size_t)q * 65536 + (size_t)o * 32;
    float sum = 0.f, ssq = 0.f;
    #pragma unroll
    for (int s4 = 0; s4 < 8; ++s4) {
        float4 a = *(const float4*)&P[pbase + s4 * 4];
        float4 b = *(const float4*)&P[2097152 + pbase + s4 * 4];
        float4 h = *(const float4*)&hr[s4 * 4];
        float4 v;
        v.x = a.x + b.x + h.x; v.y = a.y + b.y + h.y;
        v.z = a.z + b.z + h.z; v.w = a.w + b.w + h.w;
        *(float4*)&orow[s4 * 4] = v;
        sum += v.x + v.y + v.z + v.w;
        ssq += v.x * v.x + v.y * v.y + v.z * v.z + v.w * v.w;
    }
    #pragma unroll
    for (int off = 32; off > 0; off >>= 1) {
        sum += __shfl_down(sum, off);
        ssq += __shfl_down(ssq, off);
    }
    __shared__ float rs[4], rq[4];
    if ((t & 63) == 0) { rs[t >> 6] = sum; rq[t >> 6] = ssq; }
    __syncthreads();
    if (t == 0) {
        p1[q * 8 + ch] = rs[0] + rs[1] + rs[2] + rs[3];
        p2[q * 8 + ch] = rq[0] + rq[1] + rq[2] + rq[3];
    }
}

// ---------- LN2 apply (finish inline), in-place ----------
__global__ void k_ln2apply(float* __restrict__ io, const float* __restrict__ p1,
                           const float* __restrict__ p2,
                           const float* __restrict__ lnw, const float* __restrict__ lnb) {
    int q = blockIdx.x, cb = blockIdx.y;
    int t = threadIdx.x;
    float S = 0.f, Q = 0.f;
    #pragma unroll
    for (int cch = 0; cch < 8; ++cch) { S += p1[q * 8 + cch]; Q += p2[q * 8 + cch]; }
    float mu = S * (1.f / 65536.f);
    float rstd = rsqrtf(Q * (1.f / 65536.f) - mu * mu + 1e-5f);
    for (int j = 0; j < 16; ++j) {
        int i = cb * 4096 + j * 256 + t;
        float v = io[q * 65536 + i];
        io[q * 65536 + i] = (v - mu) * rstd * lnw[i] + lnb[i];
    }
}

extern "C" void kernel_launch(void* const* d_in, const int* in_sizes, int n_in,
                              void* d_out, int out_size, void* d_ws, size_t ws_size,
                              hipStream_t stream) {
    const float* x    = (const float*)d_in[0];
    const float* Wv   = (const float*)d_in[6];
    const float* bv   = (const float*)d_in[7];
    const float* Wo   = (const float*)d_in[8];
    const float* bo   = (const float*)d_in[9];
    const float* W1   = (const float*)d_in[10];
    const float* W2   = (const float*)d_in[11];
    const float* ln1w = (const float*)d_in[12];
    const float* ln1b = (const float*)d_in[13];
    const float* ln2w = (const float*)d_in[14];
    const float* ln2b = (const float*)d_in[15];
    float* out = (float*)d_out;

    float* ws    = (float*)d_ws;
    float* bvSum = ws;                    // 64
    float* p1    = ws + 128;              // 256
    float* p2    = ws + 384;              // 256
    float* Psv   = ws + 640;              // 262144
    float* Pt    = ws + 262784;           // 262144
    float* Tm    = ws + 524928;           // 65536
    float* h1    = ws + 590464;           // 2097152
    float* Pg    = ws + 2687616;          // 4194304 (2 split-K planes)
    u16* ub      = (u16*)(ws + 6881920);
    u16* WvSumb  = ub;                    // 131072
    u16* xTb     = ub + 131072;           // 2097152
    u16* h1b     = ub + 2293760;          // 2097152
    u16* Y1b     = ub + 4390912;          // 2097152
    u16* W1b     = ub + 6488064;          // 4194304
    u16* W2b     = ub + 10682368;         // 4194304
    u16* Wob     = ub + 14876672;         // 4194304

    k_prep<<<13824, 256, 0, stream>>>(W1, W2, Wo, Wv, bv, x, W1b, W2b, Wob, WvSumb, bvSum, xTb);
    k_sv_gemm<<<dim3(16, 4), 256, 0, stream>>>(WvSumb, xTb, Psv);
    k_t_gemm<<<dim3(16, 4), 256, 0, stream>>>(Wob, Psv, bvSum, Pt);
    k_t_reduce_ln1<<<dim3(32, 8), 256, 0, stream>>>(Pt, bo, x, Tm, p1, p2);
    k_ln1apply<<<dim3(32, 16), 256, 0, stream>>>(Tm, x, p1, p2, ln1w, ln1b, h1, h1b);
    // GEMM1: M=1024 (tokens) x N=2048 (o), 128x64 tile, split-K 2
    k_mfma_gemm_sk<<<dim3(8, 32, 2), 256, 0, stream>>>(h1b, W1b, Pg, 2048);
    k_g1_reduce<<<2048, 256, 0, stream>>>(Pg, Y1b);
    // GEMM2: M=2048 (o) x N=1024 (tokens), 128x64 tile, split-K 2
    k_mfma_gemm_sk<<<dim3(16, 16, 2), 256, 0, stream>>>(W2b, Y1b, Pg, 1024);
    k_g2_ln2<<<dim3(32, 8), 256, 0, stream>>>(Pg, h1, out, p1, p2);
    k_ln2apply<<<dim3(32, 16), 256, 0, stream>>>(out, p1, p2, ln2w, ln2b);
}

// Round 9
// 107.791 us; speedup vs baseline: 1.1742x; 1.0269x over previous
//
#include <hip/hip_runtime.h>

typedef unsigned short u16;
typedef unsigned int u32;
typedef unsigned long long u64;
typedef __attribute__((ext_vector_type(8))) short bf16x8;
typedef __attribute__((ext_vector_type(4))) float f32x4;

#define CCH 2048

__device__ __forceinline__ u16 f2bf(float f) {
    unsigned int x = __float_as_uint(f);
    unsigned int r = (x + 0x7fffu + ((x >> 16) & 1u)) >> 16;
    return (u16)r;
}

__device__ __forceinline__ void gload_lds16(const u16* g, u16* l) {
    __builtin_amdgcn_global_load_lds((const __attribute__((address_space(1))) void*)g,
                                     (__attribute__((address_space(3))) void*)l, 16, 0, 0);
}

// ---------- PREP: convert W1,W2,Wo -> bf16 | WvSum | x transpose ----------
__global__ void k_prep(const float* __restrict__ W1, const float* __restrict__ W2,
                       const float* __restrict__ Wo, const float* __restrict__ Wv,
                       const float* __restrict__ bv, const float* __restrict__ x,
                       u16* __restrict__ W1b, u16* __restrict__ W2b, u16* __restrict__ Wob,
                       u16* __restrict__ WvSumb, float* __restrict__ bvSum,
                       u16* __restrict__ xTb) {
    int b = blockIdx.x;
    int t = threadIdx.x;
    __shared__ float ftile[32][33];
    if (b < 12288) {
        long base = (long)b * 1024 + t * 4;
        const float* src; u16* dst; long off;
        if (base < 4194304)      { src = W1; dst = W1b; off = base; }
        else if (base < 8388608) { src = W2; dst = W2b; off = base - 4194304; }
        else                     { src = Wo; dst = Wob; off = base - 8388608; }
        float4 v = *(const float4*)&src[off];
        u64 p = (u64)f2bf(v.x) | ((u64)f2bf(v.y) << 16)
              | ((u64)f2bf(v.z) << 32) | ((u64)f2bf(v.w) << 48);
        *(u64*)&dst[off] = p;
    } else if (b < 12800) {
        int tt = (b - 12288) * 256 + t;
        int j = tt >> 11;
        float s = 0.f;
        #pragma unroll 8
        for (int m = 0; m < 32; ++m) s += Wv[(m * 64 + j) * CCH + (tt & 2047)];
        WvSumb[tt] = f2bf(s);
        if (tt < 64) {
            float bb = 0.f;
            for (int m = 0; m < 32; ++m) bb += bv[m * 64 + tt];
            bvSum[tt] = bb;
        }
    } else {
        int bb = b - 12800;
        int cb = bb & 31, q = bb >> 5;
        int c0 = cb * 64;
        u32* xT32 = (u32*)xTb;
        #pragma unroll
        for (int half = 0; half < 2; ++half) {
            int ch = c0 + half * 32;
            #pragma unroll
            for (int k = 0; k < 4; ++k) {
                int i = t + k * 256;
                ftile[i & 31][i >> 5] = x[q * 65536 + (ch + (i >> 5)) * 32 + (i & 31)];
            }
            __syncthreads();
            #pragma unroll
            for (int k = 0; k < 2; ++k) {
                int i = t + k * 256;
                int s = i >> 4, cp = i & 15;
                u32 val = (u32)f2bf(ftile[s][cp * 2]) | ((u32)f2bf(ftile[s][cp * 2 + 1]) << 16);
                xT32[(size_t)(q * 32 + s) * 1024 + (ch >> 1) + cp] = val;
            }
            __syncthreads();
        }
    }
}

// ---------- Sv GEMM: P[kc][j][col] = sum_k WvSumb[j][k] * xTb[col][k] ----------
__global__ __launch_bounds__(256) void k_sv_gemm(const u16* __restrict__ A, const u16* __restrict__ B,
                                                 float* __restrict__ P) {
    int n0 = blockIdx.x * 64;
    int kc = blockIdx.y;
    int t = threadIdx.x;
    int lane = t & 63, wid = t >> 6;
    int wm = wid * 16;
    int l15 = lane & 15, lhi = lane >> 4, sw = l15 & 7;
    int offk[2] = { ((lhi) ^ sw) * 8, ((4 + lhi) ^ sw) * 8 };
    __shared__ u16 At[2][64 * 64];
    __shared__ u16 Bt[2][64 * 64];
    f32x4 z = {0.f, 0.f, 0.f, 0.f};
    f32x4 acc[4] = {z, z, z, z};
    int srow = t >> 3, scol = ((t & 7) ^ (srow & 7)) * 8;
    int kbase = kc * 512;

    auto STAGE = [&](int p, int k0) {
        #pragma unroll
        for (int i = 0; i < 2; ++i) {
            gload_lds16(A + (size_t)(i * 32 + srow) * CCH + k0 + scol, &At[p][i * 2048 + t * 8]);
            gload_lds16(B + (size_t)(n0 + i * 32 + srow) * CCH + k0 + scol, &Bt[p][i * 2048 + t * 8]);
        }
    };
    STAGE(0, kbase);
    __syncthreads();
    int cur = 0;
    for (int kt = 0; kt < 8; ++kt) {
        if (kt < 7) STAGE(cur ^ 1, kbase + (kt + 1) * 64);
        #pragma unroll
        for (int ks = 0; ks < 2; ++ks) {
            bf16x8 af = *(const bf16x8*)&At[cur][(wm + l15) * 64 + offk[ks]];
            #pragma unroll
            for (int fn = 0; fn < 4; ++fn) {
                bf16x8 bf = *(const bf16x8*)&Bt[cur][(fn * 16 + l15) * 64 + offk[ks]];
                acc[fn] = __builtin_amdgcn_mfma_f32_16x16x32_bf16(af, bf, acc[fn], 0, 0, 0);
            }
        }
        __syncthreads();
        cur ^= 1;
    }
    #pragma unroll
    for (int fn = 0; fn < 4; ++fn)
        #pragma unroll
        for (int r = 0; r < 4; ++r) {
            int j = wm + lhi * 4 + r;
            int col = n0 + fn * 16 + l15;
            P[kc * 65536 + j * 1024 + col] = acc[fn][r];
        }
}

// ---------- Sv reduce ----------
__global__ void k_sv_reduce(const float* __restrict__ P, const float* __restrict__ bvSum,
                            u16* __restrict__ Svb) {
    int idx0 = blockIdx.x * 1024 + threadIdx.x;
    #pragma unroll
    for (int k = 0; k < 4; ++k) {
        int idx = idx0 + k * 256;
        int j = idx >> 10, col = idx & 1023;
        float v = bvSum[j];
        #pragma unroll
        for (int kc = 0; kc < 4; ++kc) v += P[kc * 65536 + idx];
        Svb[(size_t)(col >> 5) * CCH + j * 32 + (col & 31)] = f2bf(v);
    }
}

// ---------- T GEMM: P[kc][o][q] = sum_k Wob[o][k] * Svb[q][k] ----------
__global__ __launch_bounds__(256) void k_t_gemm(const u16* __restrict__ A, const u16* __restrict__ B,
                                                float* __restrict__ P) {
    int m0 = blockIdx.x * 128;
    int kc = blockIdx.y;
    int t = threadIdx.x;
    int lane = t & 63, wid = t >> 6;
    int wm = wid * 32;
    int l15 = lane & 15, lhi = lane >> 4, sw = l15 & 7;
    int offk[2] = { ((lhi) ^ sw) * 8, ((4 + lhi) ^ sw) * 8 };
    __shared__ u16 At[2][128 * 64];
    __shared__ u16 Bt[2][32 * 64];
    f32x4 z = {0.f, 0.f, 0.f, 0.f};
    f32x4 acc[2][2] = {{z, z}, {z, z}};
    int srow = t >> 3, scol = ((t & 7) ^ (srow & 7)) * 8;
    int kbase = kc * 512;

    auto STAGE = [&](int p, int k0) {
        #pragma unroll
        for (int i = 0; i < 4; ++i)
            gload_lds16(A + (size_t)(m0 + i * 32 + srow) * CCH + k0 + scol, &At[p][i * 2048 + t * 8]);
        gload_lds16(B + (size_t)srow * CCH + k0 + scol, &Bt[p][t * 8]);
    };
    STAGE(0, kbase);
    __syncthreads();
    int cur = 0;
    for (int kt = 0; kt < 8; ++kt) {
        if (kt < 7) STAGE(cur ^ 1, kbase + (kt + 1) * 64);
        #pragma unroll
        for (int ks = 0; ks < 2; ++ks) {
            bf16x8 af[2], bf[2];
            #pragma unroll
            for (int fm = 0; fm < 2; ++fm)
                af[fm] = *(const bf16x8*)&At[cur][(wm + fm * 16 + l15) * 64 + offk[ks]];
            #pragma unroll
            for (int fn = 0; fn < 2; ++fn)
                bf[fn] = *(const bf16x8*)&Bt[cur][(fn * 16 + l15) * 64 + offk[ks]];
            #pragma unroll
            for (int fm = 0; fm < 2; ++fm)
                #pragma unroll
                for (int fn = 0; fn < 2; ++fn)
                    acc[fm][fn] = __builtin_amdgcn_mfma_f32_16x16x32_bf16(af[fm], bf[fn], acc[fm][fn], 0, 0, 0);
        }
        __syncthreads();
        cur ^= 1;
    }
    #pragma unroll
    for (int fm = 0; fm < 2; ++fm)
        #pragma unroll
        for (int fn = 0; fn < 2; ++fn)
            #pragma unroll
            for (int r = 0; r < 4; ++r) {
                int mg = m0 + wm + fm * 16 + lhi * 4 + r;
                int cg = fn * 16 + l15;
                P[kc * 65536 + mg * 32 + cg] = acc[fm][fn][r];
            }
}

// ---------- fused T reduce + LN1 stats ----------
__global__ void k_t_reduce_ln1(const float* __restrict__ P, const float* __restrict__ bo,
                               const float* __restrict__ x, float* __restrict__ Tm,
                               float* __restrict__ p1, float* __restrict__ p2) {
    int q = blockIdx.x, ch = blockIdx.y;
    int t = threadIdx.x;
    int c = ch * 256 + t;
    float T = bo[c];
    #pragma unroll
    for (int kc = 0; kc < 4; ++kc) T += P[kc * 65536 + c * 32 + q];
    Tm[q * CCH + c] = T;
    float T16 = 16.f * T;
    const float* xr = x + (size_t)q * 65536 + (size_t)c * 32;
    float sum = 0.f, ssq = 0.f;
    #pragma unroll
    for (int s4 = 0; s4 < 8; ++s4) {
        float4 xv = *(const float4*)&xr[s4 * 4];
        float v0 = T16 + xv.x, v1 = T16 + xv.y, v2 = T16 + xv.z, v3 = T16 + xv.w;
        sum += v0 + v1 + v2 + v3;
        ssq += v0 * v0 + v1 * v1 + v2 * v2 + v3 * v3;
    }
    #pragma unroll
    for (int off = 32; off > 0; off >>= 1) {
        sum += __shfl_down(sum, off);
        ssq += __shfl_down(ssq, off);
    }
    __shared__ float rs[4], rq[4];
    if ((t & 63) == 0) { rs[t >> 6] = sum; rq[t >> 6] = ssq; }
    __syncthreads();
    if (t == 0) {
        p1[q * 8 + ch] = rs[0] + rs[1] + rs[2] + rs[3];
        p2[q * 8 + ch] = rq[0] + rq[1] + rq[2] + rq[3];
    }
}

// ---------- LN1 apply (finish inline) ----------
__global__ void k_ln1apply(const float* __restrict__ Tm, const float* __restrict__ x,
                           const float* __restrict__ p1, const float* __restrict__ p2,
                           const float* __restrict__ lnw, const float* __restrict__ lnb,
                           float* __restrict__ h1, u16* __restrict__ h1b) {
    int q = blockIdx.x, cb = blockIdx.y;
    int t = threadIdx.x;
    float S = 0.f, Q = 0.f;
    #pragma unroll
    for (int cch = 0; cch < 8; ++cch) { S += p1[q * 8 + cch]; Q += p2[q * 8 + cch]; }
    float mu = S * (1.f / 65536.f);
    float rstd = rsqrtf(Q * (1.f / 65536.f) - mu * mu + 1e-5f);
    __shared__ u16 tile[32 * 132];
    for (int j = 0; j < 16; ++j) {
        int i = cb * 4096 + j * 256 + t;
        float v = 16.f * Tm[q * CCH + (i >> 5)] + x[q * 65536 + i];
        float g = (v - mu) * rstd * lnw[i] + lnb[i];
        h1[q * 65536 + i] = g;
        int cl = (j * 256 + t) >> 5;
        tile[(i & 31) * 132 + cl] = f2bf(g);
    }
    __syncthreads();
    for (int j = 0; j < 16; ++j) {
        int idx = j * 256 + t;
        int s = idx >> 7, cl = idx & 127;
        h1b[(size_t)(q * 32 + s) * CCH + cb * 128 + cl] = tile[s * 132 + cl];
    }
}

// ---------- MFMA GEMM split-K 2, 128x64 tile: P[kc][m][col] ----------
__global__ __launch_bounds__(256) void k_mfma_gemm_sk(
        const u16* __restrict__ A, const u16* __restrict__ B,
        float* __restrict__ P, int ldc) {
    int m0 = blockIdx.x * 128;
    int n0 = blockIdx.y * 64;
    int kc = blockIdx.z;
    int t = threadIdx.x;
    int lane = t & 63, wid = t >> 6;
    int wm = (wid >> 1) * 64, wn = (wid & 1) * 32;
    int l15 = lane & 15, lhi = lane >> 4, sw = l15 & 7;
    int offk[2] = { ((lhi) ^ sw) * 8, ((4 + lhi) ^ sw) * 8 };

    __shared__ u16 Atile[2][128 * 64];
    __shared__ u16 Btile[2][64 * 64];

    f32x4 z = {0.f, 0.f, 0.f, 0.f};
    f32x4 acc[4][2] = {{z, z}, {z, z}, {z, z}, {z, z}};

    int srow = t >> 3;
    int scol = ((t & 7) ^ (srow & 7)) * 8;   // pre-swizzled source chunk (rule #21)
    int kbase = kc * 1024;

    auto STAGE = [&](int p, int k0) {
        #pragma unroll
        for (int i = 0; i < 4; ++i)
            gload_lds16(A + (size_t)(m0 + i * 32 + srow) * CCH + k0 + scol,
                        &Atile[p][i * 2048 + t * 8]);
        #pragma unroll
        for (int i = 0; i < 2; ++i)
            gload_lds16(B + (size_t)(n0 + i * 32 + srow) * CCH + k0 + scol,
                        &Btile[p][i * 2048 + t * 8]);
    };

    STAGE(0, kbase);
    __syncthreads();
    int cur = 0;
    for (int kt = 0; kt < 16; ++kt) {
        if (kt < 15) STAGE(cur ^ 1, kbase + (kt + 1) * 64);
        #pragma unroll
        for (int ks = 0; ks < 2; ++ks) {
            bf16x8 af[4], bf[2];
            #pragma unroll
            for (int fm = 0; fm < 4; ++fm)
                af[fm] = *(const bf16x8*)&Atile[cur][(wm + fm * 16 + l15) * 64 + offk[ks]];
            #pragma unroll
            for (int fn = 0; fn < 2; ++fn)
                bf[fn] = *(const bf16x8*)&Btile[cur][(wn + fn * 16 + l15) * 64 + offk[ks]];
            #pragma unroll
            for (int fm = 0; fm < 4; ++fm)
                #pragma unroll
                for (int fn = 0; fn < 2; ++fn)
                    acc[fm][fn] = __builtin_amdgcn_mfma_f32_16x16x32_bf16(
                        af[fm], bf[fn], acc[fm][fn], 0, 0, 0);
        }
        __syncthreads();
        cur ^= 1;
    }

    #pragma unroll
    for (int fm = 0; fm < 4; ++fm)
        #pragma unroll
        for (int fn = 0; fn < 2; ++fn)
            #pragma unroll
            for (int r = 0; r < 4; ++r) {
                int mg = m0 + wm + fm * 16 + lhi * 4 + r;
                int cg = n0 + wn + fn * 16 + l15;
                P[(size_t)kc * 2097152 + (size_t)mg * ldc + cg] = acc[fm][fn][r];
            }
}

// ---------- G1 reduce: Y1b[tok][o] = bf16(relu(P0+P1)) ----------
__global__ void k_g1_reduce(const float* __restrict__ P, u16* __restrict__ Y1b) {
    int idx = (blockIdx.x * 256 + threadIdx.x) * 4;
    float4 a = *(const float4*)&P[idx];
    float4 b = *(const float4*)&P[2097152 + idx];
    u64 p = (u64)f2bf(fmaxf(a.x + b.x, 0.f))
          | ((u64)f2bf(fmaxf(a.y + b.y, 0.f)) << 16)
          | ((u64)f2bf(fmaxf(a.z + b.z, 0.f)) << 32)
          | ((u64)f2bf(fmaxf(a.w + b.w, 0.f)) << 48);
    *(u64*)&Y1b[idx] = p;
}

// ---------- fused G2 reduce + residual + LN2 stats ----------
__global__ void k_g2_ln2(const float* __restrict__ P, const float* __restrict__ h1,
                         float* __restrict__ out, float* __restrict__ p1, float* __restrict__ p2) {
    int q = blockIdx.x, ch = blockIdx.y;
    int t = threadIdx.x;
    int o = ch * 256 + t;
    size_t pbase = (size_t)o * 1024 + q * 32;
    const float* hr = h1 + (size_t)q * 65536 + (size_t)o * 32;
    float* orow = out + (size_t)q * 65536 + (size_t)o * 32;
    float sum = 0.f, ssq = 0.f;
    #pragma unroll
    for (int s4 = 0; s4 < 8; ++s4) {
        float4 a = *(const float4*)&P[pbase + s4 * 4];
        float4 b = *(const float4*)&P[2097152 + pbase + s4 * 4];
        float4 h = *(const float4*)&hr[s4 * 4];
        float4 v;
        v.x = a.x + b.x + h.x; v.y = a.y + b.y + h.y;
        v.z = a.z + b.z + h.z; v.w = a.w + b.w + h.w;
        *(float4*)&orow[s4 * 4] = v;
        sum += v.x + v.y + v.z + v.w;
        ssq += v.x * v.x + v.y * v.y + v.z * v.z + v.w * v.w;
    }
    #pragma unroll
    for (int off = 32; off > 0; off >>= 1) {
        sum += __shfl_down(sum, off);
        ssq += __shfl_down(ssq, off);
    }
    __shared__ float rs[4], rq[4];
    if ((t & 63) == 0) { rs[t >> 6] = sum; rq[t >> 6] = ssq; }
    __syncthreads();
    if (t == 0) {
        p1[q * 8 + ch] = rs[0] + rs[1] + rs[2] + rs[3];
        p2[q * 8 + ch] = rq[0] + rq[1] + rq[2] + rq[3];
    }
}

// ---------- LN2 apply (finish inline), in-place ----------
__global__ void k_ln2apply(float* __restrict__ io, const float* __restrict__ p1,
                           const float* __restrict__ p2,
                           const float* __restrict__ lnw, const float* __restrict__ lnb) {
    int q = blockIdx.x, cb = blockIdx.y;
    int t = threadIdx.x;
    float S = 0.f, Q = 0.f;
    #pragma unroll
    for (int cch = 0; cch < 8; ++cch) { S += p1[q * 8 + cch]; Q += p2[q * 8 + cch]; }
    float mu = S * (1.f / 65536.f);
    float rstd = rsqrtf(Q * (1.f / 65536.f) - mu * mu + 1e-5f);
    for (int j = 0; j < 16; ++j) {
        int i = cb * 4096 + j * 256 + t;
        float v = io[q * 65536 + i];
        io[q * 65536 + i] = (v - mu) * rstd * lnw[i] + lnb[i];
    }
}

extern "C" void kernel_launch(void* const* d_in, const int* in_sizes, int n_in,
                              void* d_out, int out_size, void* d_ws, size_t ws_size,
                              hipStream_t stream) {
    const float* x    = (const float*)d_in[0];
    const float* Wv   = (const float*)d_in[6];
    const float* bv   = (const float*)d_in[7];
    const float* Wo   = (const float*)d_in[8];
    const float* bo   = (const float*)d_in[9];
    const float* W1   = (const float*)d_in[10];
    const float* W2   = (const float*)d_in[11];
    const float* ln1w = (const float*)d_in[12];
    const float* ln1b = (const float*)d_in[13];
    const float* ln2w = (const float*)d_in[14];
    const float* ln2b = (const float*)d_in[15];
    float* out = (float*)d_out;

    float* ws    = (float*)d_ws;
    float* bvSum = ws;                    // 64
    float* p1    = ws + 128;              // 256
    float* p2    = ws + 384;              // 256
    float* Psv   = ws + 640;              // 262144
    float* Pt    = ws + 262784;           // 262144
    float* Tm    = ws + 524928;           // 65536
    float* h1    = ws + 590464;           // 2097152
    float* Pg    = ws + 2687616;          // 4194304 (2 split-K planes)
    u16* ub      = (u16*)(ws + 6881920);
    u16* WvSumb  = ub;                    // 131072
    u16* xTb     = ub + 131072;           // 2097152
    u16* Svb     = ub + 2228224;          // 65536
    u16* h1b     = ub + 2293760;          // 2097152
    u16* Y1b     = ub + 4390912;          // 2097152
    u16* W1b     = ub + 6488064;          // 4194304
    u16* W2b     = ub + 10682368;         // 4194304
    u16* Wob     = ub + 14876672;         // 4194304

    k_prep<<<13824, 256, 0, stream>>>(W1, W2, Wo, Wv, bv, x, W1b, W2b, Wob, WvSumb, bvSum, xTb);
    k_sv_gemm<<<dim3(16, 4), 256, 0, stream>>>(WvSumb, xTb, Psv);
    k_sv_reduce<<<64, 256, 0, stream>>>(Psv, bvSum, Svb);
    k_t_gemm<<<dim3(16, 4), 256, 0, stream>>>(Wob, Svb, Pt);
    k_t_reduce_ln1<<<dim3(32, 8), 256, 0, stream>>>(Pt, bo, x, Tm, p1, p2);
    k_ln1apply<<<dim3(32, 16), 256, 0, stream>>>(Tm, x, p1, p2, ln1w, ln1b, h1, h1b);
    // GEMM1: M=1024 (tokens) x N=2048 (o), 128x64 tile, split-K 2
    k_mfma_gemm_sk<<<dim3(8, 32, 2), 256, 0, stream>>>(h1b, W1b, Pg, 2048);
    k_g1_reduce<<<2048, 256, 0, stream>>>(Pg, Y1b);
    // GEMM2: M=2048 (o) x N=1024 (tokens), 128x64 tile, split-K 2
    k_mfma_gemm_sk<<<dim3(16, 16, 2), 256, 0, stream>>>(W2b, Y1b, Pg, 1024);
    k_g2_ln2<<<dim3(32, 8), 256, 0, stream>>>(Pg, h1, out, p1, p2);
    k_ln2apply<<<dim3(32, 16), 256, 0, stream>>>(out, p1, p2, ln2w, ln2b);
}